// Round 11
// baseline (264.572 us; speedup 1.0000x reference)
//
#include <hip/hip_runtime.h>
#include <math.h>

namespace {
constexpr int kB = 2, kN = 2048, kDim = 256, kH = 8, kDH = 32;
constexpr int kBH = kB * kH;
constexpr long kPlane = (long)kBH * kN * kDH;  // 1,048,576 elems per tensor
// DH^-0.5 / ln2 folded into stored q so softmax weight = exp2(score)
constexpr float kQScaleL2 = 0.25506852552f;
}

typedef unsigned short u16;
typedef short short8 __attribute__((ext_vector_type(8)));
typedef short short4v __attribute__((ext_vector_type(4)));
typedef float floatx16 __attribute__((ext_vector_type(16)));
#define MFMA_BF16(a, b, c) __builtin_amdgcn_mfma_f32_32x32x16_bf16(a, b, c, 0, 0, 0)

__device__ inline u16 bf16b(float x) {
    union { float f; unsigned u; } c; c.f = x;
    unsigned r = c.u + 0x7FFFu + ((c.u >> 16) & 1u);
    return (u16)(r >> 16);
}
__device__ inline unsigned pack2(float x, float y) {
    return (unsigned)bf16b(x) | ((unsigned)bf16b(y) << 16);
}
// truncating bf16 pack of two positive floats via one v_perm_b32
__device__ inline unsigned packtr(float lo, float hi) {
    return __builtin_amdgcn_perm(__float_as_uint(hi), __float_as_uint(lo), 0x07060302u);
}
__device__ inline short8 mk8(const float* e) {
    union { unsigned u[4]; short8 s; } c;
    c.u[0] = packtr(e[0], e[1]);
    c.u[1] = packtr(e[2], e[3]);
    c.u[2] = packtr(e[4], e[5]);
    c.u[3] = packtr(e[6], e[7]);
    return c.s;
}
// async global->LDS: 16B per lane, LDS dest = wave-uniform base + lane*16
__device__ inline void gload16(const u16* g, u16* l) {
    __builtin_amdgcn_global_load_lds(
        (const __attribute__((address_space(1))) void*)g,
        (__attribute__((address_space(3))) void*)l, 16, 0, 0);
}

// ---------------------------------------------------------------------------
// prep v2 (unchanged from R9): LDS 64x64 tile-transposed weight prep +
// x f32->bf16 conversion into Xbf.
// ---------------------------------------------------------------------------
__global__ __launch_bounds__(256, 2) void prep_w(
    const float* __restrict__ xr_g, const float* __restrict__ xi_g,
    const float* __restrict__ wq_r, const float* __restrict__ wq_i,
    const float* __restrict__ wkv_r, const float* __restrict__ wkv_i,
    const float* __restrict__ wo_r, const float* __restrict__ wo_i,
    u16* __restrict__ Wbig, u16* __restrict__ WoT, u16* __restrict__ Xbf)
{
    const int T = blockIdx.x;
    const int tid = threadIdx.x;

    if (T < 256) {
        __shared__ __align__(16) u16 tile[64 * 68];   // [d][k2rel], pitch 68
        const float* src;
        float sgn;
        int stride, colbase, kt, dt;
        bool isWo = false;
        int g = 0, ri = 0, hi;
        if (T < 192) {
            const int p = T >> 4, q = T & 15;
            kt = (q >> 2) * 64; dt = (q & 3) * 64;
            g = p >> 1; hi = p & 1;
            if (g < 2) {
                stride = 256; colbase = dt;
                if (g == 0) { src = hi ? wq_i : wq_r; sgn = hi ? -kQScaleL2 : kQScaleL2; }
                else        { src = hi ? wq_r : wq_i; sgn = kQScaleL2; }
            } else {
                stride = 512; colbase = dt + ((g >= 4) ? 256 : 0);
                if ((g & 1) == 0) { src = hi ? wkv_i : wkv_r; sgn = hi ? -1.f : 1.f; }
                else              { src = hi ? wkv_r : wkv_i; sgn = 1.f; }
            }
        } else {
            isWo = true;
            const int pp = T - 192;
            const int qd = pp >> 4, q = pp & 15;
            ri = qd & 1; hi = qd >> 1;
            kt = (q >> 2) * 64; dt = (q & 3) * 64;
            stride = 256; colbase = dt;
            if (ri == 0) { src = hi ? wo_i : wo_r; sgn = hi ? -1.f : 1.f; }
            else         { src = hi ? wo_r : wo_i; sgn = 1.f; }
        }

        // read phase: coalesced float4 rows, transposed scalar store into LDS
        const int ti = tid >> 4, tj = tid & 15;
        #pragma unroll
        for (int rr = 0; rr < 4; ++rr) {
            const int krel = ti + rr * 16;               // k2 = kt + krel
            const float4 f = *(const float4*)(src + (long)(kt + krel) * stride
                                              + colbase + tj * 4);
            tile[(tj * 4 + 0) * 68 + krel] = bf16b(f.x * sgn);
            tile[(tj * 4 + 1) * 68 + krel] = bf16b(f.y * sgn);
            tile[(tj * 4 + 2) * 68 + krel] = bf16b(f.z * sgn);
            tile[(tj * 4 + 3) * 68 + krel] = bf16b(f.w * sgn);
        }
        __syncthreads();

        // write phase: coalesced short4 along k (16 lanes = 128B contiguous)
        const int di = tid >> 4, kj = tid & 15;
        #pragma unroll
        for (int dr = 0; dr < 4; ++dr) {
            const int dd = di + dr * 16;
            const short4v v = *(const short4v*)(tile + dd * 68 + kj * 4);
            long idx;
            if (!isWo) idx = (long)(g * 256 + dt + dd) * 512 + hi * 256 + kt + kj * 4;
            else       idx = (long)(2 * (dt + dd) + ri) * 512 + hi * 256 + kt + kj * 4;
            *(short4v*)(((!isWo) ? Wbig : WoT) + idx) = v;
        }
    } else {
        const long o = ((long)(T - 256) * 256 + tid) * 4;   // 0 .. 2097148
        const int row = (int)(o >> 9);
        const int col = (int)(o & 511);
        const float* src = (col < 256) ? (xr_g + (long)row * 256 + col)
                                       : (xi_g + (long)row * 256 + col - 256);
        const float4 f = *(const float4*)src;
        short4v v;
        v[0] = (short)bf16b(f.x); v[1] = (short)bf16b(f.y);
        v[2] = (short)bf16b(f.z); v[3] = (short)bf16b(f.w);
        *(short4v*)(Xbf + o) = v;
    }
}

// ---------------------------------------------------------------------------
// QKV projection GEMM v2 (unchanged from R7/R9).
// ---------------------------------------------------------------------------
__global__ __launch_bounds__(256, 2) void gemm_proj(
    const u16* __restrict__ Xbf, const u16* __restrict__ BT,
    u16* __restrict__ qr, u16* __restrict__ qi, u16* __restrict__ kr,
    u16* __restrict__ ki, u16* __restrict__ vrT, u16* __restrict__ viT)
{
    __shared__ __align__(16) u16 sA[2][128 * 32];
    __shared__ __align__(16) u16 sB[2][128 * 32];
    const int tid = threadIdx.x;
    const int lane = tid & 63, l31 = lane & 31, lh = lane >> 5;
    const int w = tid >> 6, wrow = w & 1, wcol = w >> 1;
    const int n0 = blockIdx.x * 128, m0 = blockIdx.y * 128;

    const int rb0 = w * 32;
    const int grow = lane >> 2;
    const int gseg = (lane & 3) * 8;

    auto stage = [&](int b, int kt) {
        #pragma unroll
        for (int half = 0; half < 2; ++half) {
            const int r = rb0 + half * 16;
            gload16(Xbf + (long)(m0 + r + grow) * 512 + kt + gseg, &sA[b][r * 32]);
            gload16(BT + (long)(n0 + r + grow) * 512 + kt + gseg, &sB[b][r * 32]);
        }
    };

    floatx16 a00 = {0}, a01 = {0}, a10 = {0}, a11 = {0};
    stage(0, 0);
    for (int it = 0; it < 16; ++it) {
        const int cur = it & 1;
        __syncthreads();                      // drains vmcnt: buf[cur] ready
        if (it < 15) stage(cur ^ 1, (it + 1) * 32);
        #pragma unroll
        for (int s = 0; s < 2; ++s) {
            const int ko = s * 16 + lh * 8;
            const short8 fa0 = *(const short8*)(&sA[cur][(wrow * 64 + l31) * 32 + ko]);
            const short8 fa1 = *(const short8*)(&sA[cur][(wrow * 64 + 32 + l31) * 32 + ko]);
            const short8 fb0 = *(const short8*)(&sB[cur][(wcol * 64 + l31) * 32 + ko]);
            const short8 fb1 = *(const short8*)(&sB[cur][(wcol * 64 + 32 + l31) * 32 + ko]);
            a00 = MFMA_BF16(fa0, fb0, a00);
            a01 = MFMA_BF16(fa0, fb1, a01);
            a10 = MFMA_BF16(fa1, fb0, a10);
            a11 = MFMA_BF16(fa1, fb1, a11);
        }
    }

    __syncthreads();   // tiles fully consumed; LDS becomes scratch
    u16* scr = ((u16*)sA) + w * 1088;

    floatx16 accs[2][2] = {{a00, a01}, {a10, a11}};
    #pragma unroll
    for (int rt = 0; rt < 2; ++rt) {
        #pragma unroll
        for (int ct = 0; ct < 2; ++ct) {
            const int colb = n0 + wcol * 64 + ct * 32;
            const int g = colb >> 8;
            const int h = (colb & 255) >> 5;
            if (g < 4) {
                u16* pl = (g == 0) ? qr : (g == 1) ? qi : (g == 2) ? kr : ki;
                #pragma unroll
                for (int reg = 0; reg < 16; ++reg) {
                    const int row = m0 + wrow * 64 + rt * 32 + (reg & 3) + 8 * (reg >> 2) + 4 * lh;
                    const int b = row >> 11, nn = row & 2047;
                    pl[(((long)(b * 8 + h)) * 2048 + nn) * 32 + l31] = bf16b(accs[rt][ct][reg]);
                }
            } else {
                // ---- coalesced vT store via wave-local LDS transpose ----
                #pragma unroll
                for (int q = 0; q < 4; ++q) {
                    union { unsigned u[2]; uint2 v; } pk;
                    pk.u[0] = pack2(accs[rt][ct][4 * q + 0], accs[rt][ct][4 * q + 1]);
                    pk.u[1] = pack2(accs[rt][ct][4 * q + 2], accs[rt][ct][4 * q + 3]);
                    *(uint2*)(scr + l31 * 34 + 8 * q + 4 * lh) = pk.v;
                }
                asm volatile("s_waitcnt lgkmcnt(0)" ::: "memory");
                const int rowb = m0 + wrow * 64 + rt * 32;
                const int b_ = rowb >> 11, nnb = rowb & 2047;
                u16* plane = (g == 4) ? vrT : viT;
                u16* rowbase = plane + ((long)(b_ * 8 + h) * 32) * 2048 + nnb;
                const int p = lane & 15;
                const int sp = (p & ~6) | ((p & 2) << 1) | ((p & 4) >> 1);
                const int dgrp = lane >> 4;
                #pragma unroll
                for (int ds_ = 0; ds_ < 8; ++ds_) {
                    const int d = ds_ * 4 + dgrp;
                    const unsigned v = *(const unsigned*)(scr + d * 34 + 2 * sp);
                    *(unsigned*)(rowbase + (long)d * 2048 + 2 * p) = v;
                }
                asm volatile("s_waitcnt lgkmcnt(0)" ::: "memory");  // scratch WAR
            }
        }
    }
}

// ---------------------------------------------------------------------------
// MFMA flash attention v11: 64 QUERIES PER WAVE (demand reduction).
// Cross-round finding: wall ~= MFMA-busy + VALU-busy + LDS demand summed
// serially; overlap is not extractable (7 variants null/worse). All waves
// of a block read IDENTICAL K/V fragments (addresses depend only on lane),
// so per-query LDS-read demand scales as 1/(queries per wave). This version
// gives each wave BOTH 32-query strips of its qtype: 2-wave 128-thread
// blocks, same 64-query window and grid, staging volume unchanged, but
// ds_read traffic + addressing issue per query HALVED (40KB -> 24KB LDS
// per block-tile). Strips processed sequentially to cap live VGPRs (~235).
// ---------------------------------------------------------------------------
__global__ __launch_bounds__(128, 2) void attn_kernel(
    const u16* __restrict__ qr_g, const u16* __restrict__ qi_g,
    const u16* __restrict__ kr_g, const u16* __restrict__ ki_g,
    const u16* __restrict__ vrT_g, const u16* __restrict__ viT_g,
    u16* __restrict__ xo)
{
    __shared__ __align__(16) u16 smem[2][2][64 * 40];   // [K/V][buf] 20.0 KiB

    const int tid = threadIdx.x;
    const int lane = tid & 63, l31 = lane & 31, lh = lane >> 5;
    const int qtype = tid >> 6;          // wave role: q_r (0) or q_i (1)
    const int bh = blockIdx.x;           // bh-major: per-XCD L2 locality
    const int i0 = blockIdx.y * 64;
    const long base = (long)bh * kN * kDH;

    // Q B-frags for BOTH strips (64 queries per wave)
    const u16* qg = (qtype ? qi_g : qr_g) + base;
    short8 qA0, qA1, qB0, qB1;
    {
        const u16* qpA = qg + (long)(i0 + l31) * kDH;
        qA0 = *(const short8*)(qpA + lh * 8);
        qA1 = *(const short8*)(qpA + 16 + lh * 8);
        const u16* qpB = qg + (long)(i0 + 32 + l31) * kDH;
        qB0 = *(const short8*)(qpB + lh * 8);
        qB1 = *(const short8*)(qpB + 16 + lh * 8);
    }

    // staging: 128 threads stage 4KB K-tile + 4KB V-tile (32B each per op)
    const int srow = tid & 63;           // K: bigkey row | V: vcol row
    const int sseg = (tid >> 6) * 16;    // elem offset 0 or 16
    const u16* kptr = ((srow < 32) ? kr_g : ki_g) + base
                    + (long)(srow & 31) * kDH + sseg;
    const u16* vptr = ((srow < 32) ? vrT_g : viT_g)
                    + ((long)bh * 32 + (srow & 31)) * kN + sseg;

    short8 k0 = *(const short8*)kptr;
    short8 k1 = *(const short8*)(kptr + 8);
    short8 v0 = *(const short8*)vptr;
    short8 v1 = *(const short8*)(vptr + 8);

    floatx16 UA0r = {0}, UA0i = {0}, UA1r = {0}, UA1i = {0};
    floatx16 UB0r = {0}, UB0i = {0}, UB1r = {0}, UB1i = {0};
    float LaA0 = 0.f, LaA1 = 0.f, LaB0 = 0.f, LaB1 = 0.f;

    for (int t = 0; t < 64; ++t) {
        u16* bK = smem[0][t & 1];
        u16* bV = smem[1][t & 1];
        *(short8*)(bK + srow * 40 + sseg) = k0;
        *(short8*)(bK + srow * 40 + sseg + 8) = k1;
        *(short8*)(bV + srow * 40 + sseg) = v0;
        *(short8*)(bV + srow * 40 + sseg + 8) = v1;
        __syncthreads();
        if (t < 63) {
            // K layout [bh][n][dh]: one 32-key tile = 1024 elems
            k0 = *(const short8*)(kptr + (long)(t + 1) * 1024);
            k1 = *(const short8*)(kptr + (long)(t + 1) * 1024 + 8);
            // vT layout [d][n]: one 32-key tile = 32 elems along n
            v0 = *(const short8*)(vptr + (t + 1) * 32);
            v1 = *(const short8*)(vptr + (t + 1) * 32 + 8);
        }

        // K A-frags (shared by both strips; read ONCE per wave)
        const short8 ka0 = *(const short8*)(bK + l31 * 40 + lh * 8);
        const short8 ka1 = *(const short8*)(bK + l31 * 40 + 16 + lh * 8);
        const short8 kb0 = *(const short8*)(bK + (32 + l31) * 40 + lh * 8);
        const short8 kb1 = *(const short8*)(bK + (32 + l31) * 40 + 16 + lh * 8);

        // ---- strip A: S -> exp/pack ----
        short8 FA0a, FA0b, FA1a, FA1b;
        {
            floatx16 S0 = {0}, S1 = {0};
            S0 = MFMA_BF16(ka0, qA0, S0);
            S0 = MFMA_BF16(ka1, qA1, S0);
            S1 = MFMA_BF16(kb0, qA0, S1);
            S1 = MFMA_BF16(kb1, qA1, S1);
            float e0[16], e1[16];
            #pragma unroll
            for (int r = 0; r < 16; ++r) {
                e0[r] = __builtin_amdgcn_exp2f(S0[r]);
                LaA0 += e0[r];
            }
            #pragma unroll
            for (int r = 0; r < 16; ++r) {
                e1[r] = __builtin_amdgcn_exp2f(S1[r]);
                LaA1 += e1[r];
            }
            FA0a = mk8(&e0[0]); FA0b = mk8(&e0[8]);
            FA1a = mk8(&e1[0]); FA1b = mk8(&e1[8]);
        }

        // ---- strip B: S -> exp/pack (S regs reused; K frags die after) ----
        short8 FB0a, FB0b, FB1a, FB1b;
        {
            floatx16 S0 = {0}, S1 = {0};
            S0 = MFMA_BF16(ka0, qB0, S0);
            S0 = MFMA_BF16(ka1, qB1, S0);
            S1 = MFMA_BF16(kb0, qB0, S1);
            S1 = MFMA_BF16(kb1, qB1, S1);
            float e0[16], e1[16];
            #pragma unroll
            for (int r = 0; r < 16; ++r) {
                e0[r] = __builtin_amdgcn_exp2f(S0[r]);
                LaB0 += e0[r];
            }
            #pragma unroll
            for (int r = 0; r < 16; ++r) {
                e1[r] = __builtin_amdgcn_exp2f(S1[r]);
                LaB1 += e1[r];
            }
            FB0a = mk8(&e0[0]); FB0b = mk8(&e0[8]);
            FB1a = mk8(&e1[0]); FB1b = mk8(&e1[8]);
        }

        // V^T A-frags (shared by both strips; read ONCE per wave)
        const short8 va0 = *(const short8*)(bV + l31 * 40 + lh * 8);
        const short8 va1 = *(const short8*)(bV + l31 * 40 + 16 + lh * 8);
        const short8 vb0 = *(const short8*)(bV + (32 + l31) * 40 + lh * 8);
        const short8 vb1 = *(const short8*)(bV + (32 + l31) * 40 + 16 + lh * 8);

        UA0r = MFMA_BF16(va0, FA0a, UA0r);
        UA0r = MFMA_BF16(va1, FA0b, UA0r);
        UA0i = MFMA_BF16(vb0, FA0a, UA0i);
        UA0i = MFMA_BF16(vb1, FA0b, UA0i);
        UA1r = MFMA_BF16(va0, FA1a, UA1r);
        UA1r = MFMA_BF16(va1, FA1b, UA1r);
        UA1i = MFMA_BF16(vb0, FA1a, UA1i);
        UA1i = MFMA_BF16(vb1, FA1b, UA1i);

        UB0r = MFMA_BF16(va0, FB0a, UB0r);
        UB0r = MFMA_BF16(va1, FB0b, UB0r);
        UB0i = MFMA_BF16(vb0, FB0a, UB0i);
        UB0i = MFMA_BF16(vb1, FB0b, UB0i);
        UB1r = MFMA_BF16(va0, FB1a, UB1r);
        UB1r = MFMA_BF16(va1, FB1b, UB1r);
        UB1i = MFMA_BF16(vb0, FB1a, UB1i);
        UB1i = MFMA_BF16(vb1, FB1b, UB1i);
    }

    LaA0 += __shfl_xor(LaA0, 32);
    LaA1 += __shfl_xor(LaA1, 32);
    LaB0 += __shfl_xor(LaB0, 32);
    LaB1 += __shfl_xor(LaB1, 32);
    const float iA0 = 1.f / LaA0, iA1 = 1.f / LaA1;
    const float iB0 = 1.f / LaB0, iB1 = 1.f / LaB1;

    float pAr[16], pAi[16], pBr[16], pBi[16];
    #pragma unroll
    for (int r = 0; r < 16; ++r) {
        if (qtype == 0) {
            pAr[r] =  UA0r[r] * iA0 - UA1i[r] * iA1;
            pAi[r] =  UA0i[r] * iA0 + UA1r[r] * iA1;
            pBr[r] =  UB0r[r] * iB0 - UB1i[r] * iB1;
            pBi[r] =  UB0i[r] * iB0 + UB1r[r] * iB1;
        } else {
            pAr[r] = -UA0i[r] * iA0 - UA1r[r] * iA1;
            pAi[r] =  UA0r[r] * iA0 - UA1i[r] * iA1;
            pBr[r] = -UB0i[r] * iB0 - UB1r[r] * iB1;
            pBi[r] =  UB0r[r] * iB0 - UB1i[r] * iB1;
        }
    }

    __syncthreads();   // done with K/V buffers; overlay combine scratch
    float* sC = (float*)smem;   // [strip][2][32 d][33]
    if (qtype == 1) {
        #pragma unroll
        for (int strip = 0; strip < 2; ++strip) {
            float* dst = sC + strip * (2 * 32 * 33);
            #pragma unroll
            for (int r = 0; r < 16; ++r) {
                const int d = (r & 3) + 8 * (r >> 2) + 4 * lh;
                dst[d * 33 + l31] = strip ? pBr[r] : pAr[r];
                dst[32 * 33 + d * 33 + l31] = strip ? pBi[r] : pAi[r];
            }
        }
    }
    __syncthreads();
    if (qtype == 0) {
        const int b = bh >> 3, h = bh & 7;
        #pragma unroll
        for (int strip = 0; strip < 2; ++strip) {
            const float* src = sC + strip * (2 * 32 * 33);
            const float* pr_ = strip ? pBr : pAr;
            const float* pi_ = strip ? pBi : pAi;
            u16* xrow = xo + ((long)(b * 2048 + i0 + strip * 32 + l31)) * 512 + h * 32;
            #pragma unroll
            for (int g = 0; g < 4; ++g) {
                const int d0 = 8 * g + 4 * lh;
                union { unsigned u[2]; uint2 v; } pr, pi;
                pr.u[0] = pack2(pr_[4 * g + 0] + src[(d0 + 0) * 33 + l31],
                                pr_[4 * g + 1] + src[(d0 + 1) * 33 + l31]);
                pr.u[1] = pack2(pr_[4 * g + 2] + src[(d0 + 2) * 33 + l31],
                                pr_[4 * g + 3] + src[(d0 + 3) * 33 + l31]);
                pi.u[0] = pack2(pi_[4 * g + 0] + src[32 * 33 + (d0 + 0) * 33 + l31],
                                pi_[4 * g + 1] + src[32 * 33 + (d0 + 1) * 33 + l31]);
                pi.u[1] = pack2(pi_[4 * g + 2] + src[32 * 33 + (d0 + 2) * 33 + l31],
                                pi_[4 * g + 3] + src[32 * 33 + (d0 + 3) * 33 + l31]);
                *(uint2*)(xrow + d0) = pr.v;
                *(uint2*)(xrow + 256 + d0) = pi.v;
            }
        }
    }
}

// ---------------------------------------------------------------------------
// Output projection GEMM v2 (unchanged from R7/R9).
// ---------------------------------------------------------------------------
__global__ __launch_bounds__(256, 2) void gemm_oproj(
    const u16* __restrict__ Xo, const u16* __restrict__ BT, float* __restrict__ out)
{
    __shared__ __align__(16) u16 sA[2][64 * 32];
    __shared__ __align__(16) u16 sB[2][64 * 32];
    const int tid = threadIdx.x;
    const int lane = tid & 63, l31 = lane & 31, lh = lane >> 5;
    const int w = tid >> 6, wrow = w & 1, wcol = w >> 1;
    const int n0 = blockIdx.x * 64, m0 = blockIdx.y * 64;

    const int rb0 = w * 16;
    const int grow = lane >> 2;
    const int gseg = (lane & 3) * 8;

    auto stage = [&](int b, int kt) {
        gload16(Xo + (long)(m0 + rb0 + grow) * 512 + kt + gseg, &sA[b][rb0 * 32]);
        gload16(BT + (long)(n0 + rb0 + grow) * 512 + kt + gseg, &sB[b][rb0 * 32]);
    };

    floatx16 acc = {0};
    stage(0, 0);
    for (int it = 0; it < 16; ++it) {
        const int cur = it & 1;
        __syncthreads();
        if (it < 15) stage(cur ^ 1, (it + 1) * 32);
        #pragma unroll
        for (int s = 0; s < 2; ++s) {
            const int ko = s * 16 + lh * 8;
            const short8 fa = *(const short8*)(&sA[cur][(wrow * 32 + l31) * 32 + ko]);
            const short8 fb = *(const short8*)(&sB[cur][(wcol * 32 + l31) * 32 + ko]);
            acc = MFMA_BF16(fa, fb, acc);
        }
    }

    const int col = n0 + wcol * 32 + l31;
    #pragma unroll
    for (int reg = 0; reg < 16; ++reg) {
        const int row = m0 + wrow * 32 + (reg & 3) + 8 * (reg >> 2) + 4 * lh;
        out[(long)row * 512 + col] = acc[reg];
    }
}

extern "C" void kernel_launch(void* const* d_in, const int* in_sizes, int n_in,
                              void* d_out, int out_size, void* d_ws, size_t ws_size,
                              hipStream_t stream) {
    const float* xr    = (const float*)d_in[0];
    const float* xi    = (const float*)d_in[1];
    const float* wq_r  = (const float*)d_in[2];
    const float* wq_i  = (const float*)d_in[3];
    const float* wkv_r = (const float*)d_in[4];
    const float* wkv_i = (const float*)d_in[5];
    const float* wo_r  = (const float*)d_in[6];
    const float* wo_i  = (const float*)d_in[7];
    float* out = (float*)d_out;

    u16* ws16 = (u16*)d_ws;
    u16* qr   = ws16 + 0 * kPlane;
    u16* qi   = ws16 + 1 * kPlane;
    u16* kr   = ws16 + 2 * kPlane;
    u16* ki   = ws16 + 3 * kPlane;
    u16* vrT  = ws16 + 4 * kPlane;
    u16* viT  = ws16 + 5 * kPlane;
    u16* xo   = ws16 + 6 * kPlane;               // 2,097,152 elems
    u16* Wbig = ws16 + 8 * kPlane;               // 786,432 elems
    u16* WoT  = Wbig + 786432;                   // 262,144 elems
    u16* Xbf  = xo;    // time-shared: Xbf consumed by gemm_proj before attn writes xo

    prep_w<<<2304, 256, 0, stream>>>(xr, xi, wq_r, wq_i, wkv_r, wkv_i, wo_r, wo_i,
                                     Wbig, WoT, Xbf);
    gemm_proj<<<dim3(12, 32), 256, 0, stream>>>(Xbf, Wbig, qr, qi, kr, ki, vrT, viT);
    attn_kernel<<<dim3(kBH, kN / 64), 128, 0, stream>>>(qr, qi, kr, ki, vrT, viT, xo);
    gemm_oproj<<<dim3(8, 64), 256, 0, stream>>>(xo, WoT, out);
}

// Round 12
// 162.637 us; speedup vs baseline: 1.6268x; 1.6268x over previous
//
#include <hip/hip_runtime.h>
#include <math.h>

namespace {
constexpr int kB = 2, kN = 2048, kDim = 256, kH = 8, kDH = 32;
constexpr int kBH = kB * kH;
constexpr long kPlane = (long)kBH * kN * kDH;  // 1,048,576 elems per tensor
// DH^-0.5 / ln2 folded into stored q so softmax weight = exp2(score)
constexpr float kQScaleL2 = 0.25506852552f;
}

typedef unsigned short u16;
typedef short short8 __attribute__((ext_vector_type(8)));
typedef short short4v __attribute__((ext_vector_type(4)));
typedef float floatx16 __attribute__((ext_vector_type(16)));
#define MFMA_BF16(a, b, c) __builtin_amdgcn_mfma_f32_32x32x16_bf16(a, b, c, 0, 0, 0)

__device__ inline u16 bf16b(float x) {
    union { float f; unsigned u; } c; c.f = x;
    unsigned r = c.u + 0x7FFFu + ((c.u >> 16) & 1u);
    return (u16)(r >> 16);
}
__device__ inline unsigned pack2(float x, float y) {
    return (unsigned)bf16b(x) | ((unsigned)bf16b(y) << 16);
}
// truncating bf16 pack of two positive floats via one v_perm_b32
__device__ inline unsigned packtr(float lo, float hi) {
    return __builtin_amdgcn_perm(__float_as_uint(hi), __float_as_uint(lo), 0x07060302u);
}
__device__ inline short8 mk8(const float* e) {
    union { unsigned u[4]; short8 s; } c;
    c.u[0] = packtr(e[0], e[1]);
    c.u[1] = packtr(e[2], e[3]);
    c.u[2] = packtr(e[4], e[5]);
    c.u[3] = packtr(e[6], e[7]);
    return c.s;
}
// async global->LDS: 16B per lane, LDS dest = wave-uniform base + lane*16
__device__ inline void gload16(const u16* g, u16* l) {
    __builtin_amdgcn_global_load_lds(
        (const __attribute__((address_space(1))) void*)g,
        (__attribute__((address_space(3))) void*)l, 16, 0, 0);
}

// ---------------------------------------------------------------------------
// prep v2 (R9, verified): LDS 64x64 tile-transposed weight prep +
// x f32->bf16 conversion into Xbf.
// ---------------------------------------------------------------------------
__global__ __launch_bounds__(256, 2) void prep_w(
    const float* __restrict__ xr_g, const float* __restrict__ xi_g,
    const float* __restrict__ wq_r, const float* __restrict__ wq_i,
    const float* __restrict__ wkv_r, const float* __restrict__ wkv_i,
    const float* __restrict__ wo_r, const float* __restrict__ wo_i,
    u16* __restrict__ Wbig, u16* __restrict__ WoT, u16* __restrict__ Xbf)
{
    const int T = blockIdx.x;
    const int tid = threadIdx.x;

    if (T < 256) {
        __shared__ __align__(16) u16 tile[64 * 68];   // [d][k2rel], pitch 68
        const float* src;
        float sgn;
        int stride, colbase, kt, dt;
        bool isWo = false;
        int g = 0, ri = 0, hi;
        if (T < 192) {
            const int p = T >> 4, q = T & 15;
            kt = (q >> 2) * 64; dt = (q & 3) * 64;
            g = p >> 1; hi = p & 1;
            if (g < 2) {
                stride = 256; colbase = dt;
                if (g == 0) { src = hi ? wq_i : wq_r; sgn = hi ? -kQScaleL2 : kQScaleL2; }
                else        { src = hi ? wq_r : wq_i; sgn = kQScaleL2; }
            } else {
                stride = 512; colbase = dt + ((g >= 4) ? 256 : 0);
                if ((g & 1) == 0) { src = hi ? wkv_i : wkv_r; sgn = hi ? -1.f : 1.f; }
                else              { src = hi ? wkv_r : wkv_i; sgn = 1.f; }
            }
        } else {
            isWo = true;
            const int pp = T - 192;
            const int qd = pp >> 4, q = pp & 15;
            ri = qd & 1; hi = qd >> 1;
            kt = (q >> 2) * 64; dt = (q & 3) * 64;
            stride = 256; colbase = dt;
            if (ri == 0) { src = hi ? wo_i : wo_r; sgn = hi ? -1.f : 1.f; }
            else         { src = hi ? wo_r : wo_i; sgn = 1.f; }
        }

        // read phase: coalesced float4 rows, transposed scalar store into LDS
        const int ti = tid >> 4, tj = tid & 15;
        #pragma unroll
        for (int rr = 0; rr < 4; ++rr) {
            const int krel = ti + rr * 16;               // k2 = kt + krel
            const float4 f = *(const float4*)(src + (long)(kt + krel) * stride
                                              + colbase + tj * 4);
            tile[(tj * 4 + 0) * 68 + krel] = bf16b(f.x * sgn);
            tile[(tj * 4 + 1) * 68 + krel] = bf16b(f.y * sgn);
            tile[(tj * 4 + 2) * 68 + krel] = bf16b(f.z * sgn);
            tile[(tj * 4 + 3) * 68 + krel] = bf16b(f.w * sgn);
        }
        __syncthreads();

        // write phase: coalesced short4 along k (16 lanes = 128B contiguous)
        const int di = tid >> 4, kj = tid & 15;
        #pragma unroll
        for (int dr = 0; dr < 4; ++dr) {
            const int dd = di + dr * 16;
            const short4v v = *(const short4v*)(tile + dd * 68 + kj * 4);
            long idx;
            if (!isWo) idx = (long)(g * 256 + dt + dd) * 512 + hi * 256 + kt + kj * 4;
            else       idx = (long)(2 * (dt + dd) + ri) * 512 + hi * 256 + kt + kj * 4;
            *(short4v*)(((!isWo) ? Wbig : WoT) + idx) = v;
        }
    } else {
        const long o = ((long)(T - 256) * 256 + tid) * 4;   // 0 .. 2097148
        const int row = (int)(o >> 9);
        const int col = (int)(o & 511);
        const float* src = (col < 256) ? (xr_g + (long)row * 256 + col)
                                       : (xi_g + (long)row * 256 + col - 256);
        const float4 f = *(const float4*)src;
        short4v v;
        v[0] = (short)bf16b(f.x); v[1] = (short)bf16b(f.y);
        v[2] = (short)bf16b(f.z); v[3] = (short)bf16b(f.w);
        *(short4v*)(Xbf + o) = v;
    }
}

// ---------------------------------------------------------------------------
// QKV projection GEMM v2 (R7/R9, verified).
// ---------------------------------------------------------------------------
__global__ __launch_bounds__(256, 2) void gemm_proj(
    const u16* __restrict__ Xbf, const u16* __restrict__ BT,
    u16* __restrict__ qr, u16* __restrict__ qi, u16* __restrict__ kr,
    u16* __restrict__ ki, u16* __restrict__ vrT, u16* __restrict__ viT)
{
    __shared__ __align__(16) u16 sA[2][128 * 32];
    __shared__ __align__(16) u16 sB[2][128 * 32];
    const int tid = threadIdx.x;
    const int lane = tid & 63, l31 = lane & 31, lh = lane >> 5;
    const int w = tid >> 6, wrow = w & 1, wcol = w >> 1;
    const int n0 = blockIdx.x * 128, m0 = blockIdx.y * 128;

    const int rb0 = w * 32;
    const int grow = lane >> 2;
    const int gseg = (lane & 3) * 8;

    auto stage = [&](int b, int kt) {
        #pragma unroll
        for (int half = 0; half < 2; ++half) {
            const int r = rb0 + half * 16;
            gload16(Xbf + (long)(m0 + r + grow) * 512 + kt + gseg, &sA[b][r * 32]);
            gload16(BT + (long)(n0 + r + grow) * 512 + kt + gseg, &sB[b][r * 32]);
        }
    };

    floatx16 a00 = {0}, a01 = {0}, a10 = {0}, a11 = {0};
    stage(0, 0);
    for (int it = 0; it < 16; ++it) {
        const int cur = it & 1;
        __syncthreads();                      // drains vmcnt: buf[cur] ready
        if (it < 15) stage(cur ^ 1, (it + 1) * 32);
        #pragma unroll
        for (int s = 0; s < 2; ++s) {
            const int ko = s * 16 + lh * 8;
            const short8 fa0 = *(const short8*)(&sA[cur][(wrow * 64 + l31) * 32 + ko]);
            const short8 fa1 = *(const short8*)(&sA[cur][(wrow * 64 + 32 + l31) * 32 + ko]);
            const short8 fb0 = *(const short8*)(&sB[cur][(wcol * 64 + l31) * 32 + ko]);
            const short8 fb1 = *(const short8*)(&sB[cur][(wcol * 64 + 32 + l31) * 32 + ko]);
            a00 = MFMA_BF16(fa0, fb0, a00);
            a01 = MFMA_BF16(fa0, fb1, a01);
            a10 = MFMA_BF16(fa1, fb0, a10);
            a11 = MFMA_BF16(fa1, fb1, a11);
        }
    }

    __syncthreads();   // tiles fully consumed; LDS becomes scratch
    u16* scr = ((u16*)sA) + w * 1088;

    floatx16 accs[2][2] = {{a00, a01}, {a10, a11}};
    #pragma unroll
    for (int rt = 0; rt < 2; ++rt) {
        #pragma unroll
        for (int ct = 0; ct < 2; ++ct) {
            const int colb = n0 + wcol * 64 + ct * 32;
            const int g = colb >> 8;
            const int h = (colb & 255) >> 5;
            if (g < 4) {
                u16* pl = (g == 0) ? qr : (g == 1) ? qi : (g == 2) ? kr : ki;
                #pragma unroll
                for (int reg = 0; reg < 16; ++reg) {
                    const int row = m0 + wrow * 64 + rt * 32 + (reg & 3) + 8 * (reg >> 2) + 4 * lh;
                    const int b = row >> 11, nn = row & 2047;
                    pl[(((long)(b * 8 + h)) * 2048 + nn) * 32 + l31] = bf16b(accs[rt][ct][reg]);
                }
            } else {
                // ---- coalesced vT store via wave-local LDS transpose ----
                #pragma unroll
                for (int q = 0; q < 4; ++q) {
                    union { unsigned u[2]; uint2 v; } pk;
                    pk.u[0] = pack2(accs[rt][ct][4 * q + 0], accs[rt][ct][4 * q + 1]);
                    pk.u[1] = pack2(accs[rt][ct][4 * q + 2], accs[rt][ct][4 * q + 3]);
                    *(uint2*)(scr + l31 * 34 + 8 * q + 4 * lh) = pk.v;
                }
                asm volatile("s_waitcnt lgkmcnt(0)" ::: "memory");
                const int rowb = m0 + wrow * 64 + rt * 32;
                const int b_ = rowb >> 11, nnb = rowb & 2047;
                u16* plane = (g == 4) ? vrT : viT;
                u16* rowbase = plane + ((long)(b_ * 8 + h) * 32) * 2048 + nnb;
                const int p = lane & 15;
                const int sp = (p & ~6) | ((p & 2) << 1) | ((p & 4) >> 1);
                const int dgrp = lane >> 4;
                #pragma unroll
                for (int ds_ = 0; ds_ < 8; ++ds_) {
                    const int d = ds_ * 4 + dgrp;
                    const unsigned v = *(const unsigned*)(scr + d * 34 + 2 * sp);
                    *(unsigned*)(rowbase + (long)d * 2048 + 2 * p) = v;
                }
                asm volatile("s_waitcnt lgkmcnt(0)" ::: "memory");  // scratch WAR
            }
        }
    }
}

// ---------------------------------------------------------------------------
// MFMA flash attention (R0/R9 version, 62-63 us measured -- proven best).
// MFMA-busy = 22us = the bf16 ubench floor for 51.5 GFLOP; VALU/trans
// demand ~28us intrinsic; 8 restructures (no-LDS K, replica waves, 64-key
// tiles, S-pipeline, deferred PV, ones-MFMA, 64q/wave) all null/worse.
// ---------------------------------------------------------------------------
__global__ __launch_bounds__(256, 2) void attn_kernel(
    const u16* __restrict__ qr_g, const u16* __restrict__ qi_g,
    const u16* __restrict__ kr_g, const u16* __restrict__ ki_g,
    const u16* __restrict__ vrT_g, const u16* __restrict__ viT_g,
    u16* __restrict__ xo)
{
    __shared__ __align__(16) u16 smem[2][2][64 * 40];   // [K/V][buf] 20.0 KiB

    const int tid = threadIdx.x;
    const int lane = tid & 63, l31 = lane & 31, lh = lane >> 5;
    const int w = tid >> 6, strip = w & 1, qtype = w >> 1;
    const int bh = blockIdx.x;          // bh-major: per-XCD L2 locality
    const int i0 = blockIdx.y * 64;
    const long base = (long)bh * kN * kDH;

    // Q B-frags (lane = query column l31, k = d)
    const u16* qg = (qtype ? qi_g : qr_g) + base;
    short8 qB0, qB1;
    {
        const u16* qp = qg + (long)(i0 + strip * 32 + l31) * kDH;
        qB0 = *(const short8*)(qp + lh * 8);
        qB1 = *(const short8*)(qp + 16 + lh * 8);
    }

    // staging roles: one b128 per thread for K and V
    const int srow = tid & 63;   // K: bigkey row | V: vcol row
    const int sseg = tid >> 6;   // 8-elem segment
    const u16* kptr = ((srow < 32) ? kr_g : ki_g) + base
                    + (long)(srow & 31) * kDH + sseg * 8;
    const u16* vptr = ((srow < 32) ? vrT_g : viT_g)
                    + ((long)bh * 32 + (srow & 31)) * kN + sseg * 8;

    short8 kreg = *(const short8*)kptr;
    short8 vreg = *(const short8*)vptr;

    floatx16 U0r = {0}, U0i = {0}, U1r = {0}, U1i = {0};
    float La0 = 0.f, La1 = 0.f;

    for (int t = 0; t < 64; ++t) {
        u16* bK = smem[0][t & 1];
        u16* bV = smem[1][t & 1];
        *(short8*)(bK + srow * 40 + sseg * 8) = kreg;
        *(short8*)(bV + srow * 40 + sseg * 8) = vreg;
        __syncthreads();
        if (t < 63) {
            // K layout [bh][n][dh]: one 32-key tile = 1024 elems
            kreg = *(const short8*)(kptr + (long)(t + 1) * 1024);
            // vT layout [d][n]: one 32-key tile = 32 elems along n
            vreg = *(const short8*)(vptr + (t + 1) * 32);
        }

        // S^T: A = K rows (kr: 0..31, ki: 32..63), B = Q
        const short8 ka0 = *(const short8*)(bK + l31 * 40 + lh * 8);
        const short8 ka1 = *(const short8*)(bK + l31 * 40 + 16 + lh * 8);
        const short8 kb0 = *(const short8*)(bK + (32 + l31) * 40 + lh * 8);
        const short8 kb1 = *(const short8*)(bK + (32 + l31) * 40 + 16 + lh * 8);
        floatx16 S0 = {0}, S1 = {0};
        S0 = MFMA_BF16(ka0, qB0, S0);
        S0 = MFMA_BF16(ka1, qB1, S0);
        S1 = MFMA_BF16(kb0, qB0, S1);
        S1 = MFMA_BF16(kb1, qB1, S1);

        float e0[16], e1[16];
        #pragma unroll
        for (int r = 0; r < 16; ++r) {
            e0[r] = __builtin_amdgcn_exp2f(S0[r]);
            La0 += e0[r];
        }
        #pragma unroll
        for (int r = 0; r < 16; ++r) {
            e1[r] = __builtin_amdgcn_exp2f(S1[r]);
            La1 += e1[r];
        }
        // PV B-frags from own regs (permutation pre-applied in V layout)
        const short8 F0a = mk8(&e0[0]);
        const short8 F0b = mk8(&e0[8]);
        const short8 F1a = mk8(&e1[0]);
        const short8 F1b = mk8(&e1[8]);

        // V^T A-frags (vr rows 0..31, vi rows 32..63)
        const short8 va0 = *(const short8*)(bV + l31 * 40 + lh * 8);
        const short8 va1 = *(const short8*)(bV + l31 * 40 + 16 + lh * 8);
        const short8 vb0 = *(const short8*)(bV + (32 + l31) * 40 + lh * 8);
        const short8 vb1 = *(const short8*)(bV + (32 + l31) * 40 + 16 + lh * 8);

        U0r = MFMA_BF16(va0, F0a, U0r);
        U0r = MFMA_BF16(va1, F0b, U0r);
        U0i = MFMA_BF16(vb0, F0a, U0i);
        U0i = MFMA_BF16(vb1, F0b, U0i);
        U1r = MFMA_BF16(va0, F1a, U1r);
        U1r = MFMA_BF16(va1, F1b, U1r);
        U1i = MFMA_BF16(vb0, F1a, U1i);
        U1i = MFMA_BF16(vb1, F1b, U1i);
    }

    La0 += __shfl_xor(La0, 32);
    La1 += __shfl_xor(La1, 32);
    const float iL0 = 1.f / La0, iL1 = 1.f / La1;

    float po_r[16], po_i[16];
    #pragma unroll
    for (int r = 0; r < 16; ++r) {
        if (qtype == 0) {
            po_r[r] =  U0r[r] * iL0 - U1i[r] * iL1;
            po_i[r] =  U0i[r] * iL0 + U1r[r] * iL1;
        } else {
            po_r[r] = -U0i[r] * iL0 - U1r[r] * iL1;
            po_i[r] =  U0r[r] * iL0 - U1i[r] * iL1;
        }
    }

    __syncthreads();   // done with K/V buffers; overlay combine scratch
    float* sC = (float*)smem;   // [strip][2][32 d][33]
    if (qtype == 1) {
        float* dst = sC + strip * (2 * 32 * 33);
        #pragma unroll
        for (int r = 0; r < 16; ++r) {
            const int d = (r & 3) + 8 * (r >> 2) + 4 * lh;
            dst[d * 33 + l31] = po_r[r];
            dst[32 * 33 + d * 33 + l31] = po_i[r];
        }
    }
    __syncthreads();
    if (qtype == 0) {
        const float* src = sC + strip * (2 * 32 * 33);
        const int b = bh >> 3, h = bh & 7;
        u16* xrow = xo + ((long)(b * 2048 + i0 + strip * 32 + l31)) * 512 + h * 32;
        #pragma unroll
        for (int g = 0; g < 4; ++g) {
            const int d0 = 8 * g + 4 * lh;
            union { unsigned u[2]; uint2 v; } pr, pi;
            pr.u[0] = pack2(po_r[4 * g + 0] + src[(d0 + 0) * 33 + l31],
                            po_r[4 * g + 1] + src[(d0 + 1) * 33 + l31]);
            pr.u[1] = pack2(po_r[4 * g + 2] + src[(d0 + 2) * 33 + l31],
                            po_r[4 * g + 3] + src[(d0 + 3) * 33 + l31]);
            pi.u[0] = pack2(po_i[4 * g + 0] + src[32 * 33 + (d0 + 0) * 33 + l31],
                            po_i[4 * g + 1] + src[32 * 33 + (d0 + 1) * 33 + l31]);
            pi.u[1] = pack2(po_i[4 * g + 2] + src[32 * 33 + (d0 + 2) * 33 + l31],
                            po_i[4 * g + 3] + src[32 * 33 + (d0 + 3) * 33 + l31]);
            *(uint2*)(xrow + d0) = pr.v;
            *(uint2*)(xrow + 256 + d0) = pi.v;
        }
    }
}

// ---------------------------------------------------------------------------
// Output projection GEMM v2 (R7/R9, verified).
// ---------------------------------------------------------------------------
__global__ __launch_bounds__(256, 2) void gemm_oproj(
    const u16* __restrict__ Xo, const u16* __restrict__ BT, float* __restrict__ out)
{
    __shared__ __align__(16) u16 sA[2][64 * 32];
    __shared__ __align__(16) u16 sB[2][64 * 32];
    const int tid = threadIdx.x;
    const int lane = tid & 63, l31 = lane & 31, lh = lane >> 5;
    const int w = tid >> 6, wrow = w & 1, wcol = w >> 1;
    const int n0 = blockIdx.x * 64, m0 = blockIdx.y * 64;

    const int rb0 = w * 16;
    const int grow = lane >> 2;
    const int gseg = (lane & 3) * 8;

    auto stage = [&](int b, int kt) {
        gload16(Xo + (long)(m0 + rb0 + grow) * 512 + kt + gseg, &sA[b][rb0 * 32]);
        gload16(BT + (long)(n0 + rb0 + grow) * 512 + kt + gseg, &sB[b][rb0 * 32]);
    };

    floatx16 acc = {0};
    stage(0, 0);
    for (int it = 0; it < 16; ++it) {
        const int cur = it & 1;
        __syncthreads();
        if (it < 15) stage(cur ^ 1, (it + 1) * 32);
        #pragma unroll
        for (int s = 0; s < 2; ++s) {
            const int ko = s * 16 + lh * 8;
            const short8 fa = *(const short8*)(&sA[cur][(wrow * 32 + l31) * 32 + ko]);
            const short8 fb = *(const short8*)(&sB[cur][(wcol * 32 + l31) * 32 + ko]);
            acc = MFMA_BF16(fa, fb, acc);
        }
    }

    const int col = n0 + wcol * 32 + l31;
    #pragma unroll
    for (int reg = 0; reg < 16; ++reg) {
        const int row = m0 + wrow * 32 + (reg & 3) + 8 * (reg >> 2) + 4 * lh;
        out[(long)row * 512 + col] = acc[reg];
    }
}

extern "C" void kernel_launch(void* const* d_in, const int* in_sizes, int n_in,
                              void* d_out, int out_size, void* d_ws, size_t ws_size,
                              hipStream_t stream) {
    const float* xr    = (const float*)d_in[0];
    const float* xi    = (const float*)d_in[1];
    const float* wq_r  = (const float*)d_in[2];
    const float* wq_i  = (const float*)d_in[3];
    const float* wkv_r = (const float*)d_in[4];
    const float* wkv_i = (const float*)d_in[5];
    const float* wo_r  = (const float*)d_in[6];
    const float* wo_i  = (const float*)d_in[7];
    float* out = (float*)d_out;

    u16* ws16 = (u16*)d_ws;
    u16* qr   = ws16 + 0 * kPlane;
    u16* qi   = ws16 + 1 * kPlane;
    u16* kr   = ws16 + 2 * kPlane;
    u16* ki   = ws16 + 3 * kPlane;
    u16* vrT  = ws16 + 4 * kPlane;
    u16* viT  = ws16 + 5 * kPlane;
    u16* xo   = ws16 + 6 * kPlane;               // 2,097,152 elems
    u16* Wbig = ws16 + 8 * kPlane;               // 786,432 elems
    u16* WoT  = Wbig + 786432;                   // 262,144 elems
    u16* Xbf  = xo;    // time-shared: Xbf consumed by gemm_proj before attn writes xo

    prep_w<<<2304, 256, 0, stream>>>(xr, xi, wq_r, wq_i, wkv_r, wkv_i, wo_r, wo_i,
                                     Wbig, WoT, Xbf);
    gemm_proj<<<dim3(12, 32), 256, 0, stream>>>(Xbf, Wbig, qr, qi, kr, ki, vrT, viT);
    attn_kernel<<<dim3(kBH, kN / 64), 256, 0, stream>>>(qr, qi, kr, ki, vrT, viT, xo);
    gemm_oproj<<<dim3(8, 64), 256, 0, stream>>>(xo, WoT, out);
}